// Round 3
// baseline (146.083 us; speedup 1.0000x reference)
//
#include <hip/hip_runtime.h>
#include <math.h>

// Problem constants (fixed by reference setup_inputs): pred [32,1,512,512] f32
#define IMG_W 512
#define IMG_H 512
#define HW (IMG_W * IMG_H)      // 262144 = 2^18
#define LOGHW 18
#define NIMG 32
#define NTOT (NIMG * HW)        // 8388608
#define TILE 64
#define TPI 64                  // 8x8 tiles of 64x64 per image
#define NTILE (NIMG * TPI)      // 2048
#define EDGE_N (NTILE * 64)     // 131072 entries per edge direction
#define NPAIR (NIMG * 112)      // 56 vertical + 56 horizontal tile-pairs/img
#define RTSTRIDE 2048           // max roots per 64x64 tile (checkerboard bound)
#define DEMCAP 4096             // max demotions/img (<= 112 pairs * 32 runs)
// NOTE (R6/R15): NO cross-block handshakes inside large grids; 32-way counter
// in the 32-block k_tail grid is the only safe pattern.
// NOTE (R12): no big register prefetch in k_local — occupancy > prefetch.
// NOTE (R8..R14): k_local latency floor ~42-46us; harness fixed cost ~55us
// in-window (256MiB ws poison fill = 44us at HBM ceiling — untouchable).
// NOTE (R16/R17 lesson): scattered per-candidate global probes in a
// 32-block k_tail are dependent-latency serialized (~1.5us per K candidates);
// per-pixel VALU added to k_local's hot passes costs +6us. Fixes: export
// sparse data from diverged paths only; NEVER probe — count.
// R18: k_border exports DEMOTED roots (a root is demoted exactly once, at the
// successful atomicMin old==a). k_tail: num = sumLocalRoots - demotions;
// last_root = max over rootList entries not in the LDS demoted-bitmap.
// Coalesced reads only; zero scattered global probes.

// ---------------- lock-free min-index union-find ----------------------------
__device__ __forceinline__ void uf_unite(int* L, int a, int b) {
    while (true) {
        int p = ((volatile int*)L)[a];
        while (p != a) { a = p; p = ((volatile int*)L)[a]; }
        p = ((volatile int*)L)[b];
        while (p != b) { b = p; p = ((volatile int*)L)[b]; }
        if (a == b) return;
        if (a < b) { int t = a; a = b; b = t; }  // a > b
        int old = atomicMin(&L[a], b);
        if (old == a) return;
        a = old;
    }
}

// Variant returning the demoted root (-1 if the two were already united).
// Parent pointers only decrease and L[x] <= x always, so L[a]==a can flip to
// L[a]<a exactly once per index a, and only via the old==a success below.
__device__ __forceinline__ int uf_unite_dem(int* L, int a, int b) {
    while (true) {
        int p = ((volatile int*)L)[a];
        while (p != a) { a = p; p = ((volatile int*)L)[a]; }
        p = ((volatile int*)L)[b];
        while (p != b) { b = p; p = ((volatile int*)L)[b]; }
        if (a == b) return -1;
        if (a < b) { int t = a; a = b; b = t; }  // a > b
        int old = atomicMin(&L[a], b);
        if (old == a) return a;                  // root a demoted (unique)
        a = old;
    }
}

// ---------------- K1: CCL + base BCE + edge export + root-list export -------
// One block (512 thr, 8 waves) per 64x64 tile; row width == wave width.
// Pass 1: row-run labels via ballot + fused base BCE sum.
// Pass 2: vertical unites only at contact-run starts (~750/tile).
// Pass 3a: run-starts chase to root; roots (x==i, ~270/tile) append their
//   image-local index to this tile's rootList segment (LDS counter, sparse).
// Pass 3b: every px root = lab[lab[px]] (b128 read + gather); write global L.
__global__ __launch_bounds__(512) void k_local(const float* __restrict__ pred,
                                               int* __restrict__ L,
                                               float* __restrict__ partials,
                                               int* __restrict__ edges,
                                               int* __restrict__ rootCnt,
                                               int* __restrict__ rootList,
                                               int* __restrict__ demCnt,
                                               unsigned int* __restrict__ counter) {
    __shared__ int lab[TILE * TILE];   // 16 KB
    __shared__ float swf[8];
    __shared__ int rootc;
    int tile = blockIdx.x;
    int img = tile >> 6;
    int t = tile & (TPI - 1);
    int ty = t >> 3, tx = t & 7;
    int baseLocal = (ty * TILE) * IMG_W + tx * TILE;  // image-local origin
    const float* pi = pred + ((size_t)img << LOGHW);
    int* Li = L + ((size_t)img << LOGHW);
    int tid = threadIdx.x;
    int lane = tid & 63, wave = tid >> 6;             // wave 0..7
    if (tid == 0) rootc = 0;
    if (blockIdx.x == 0 && tid < NIMG) demCnt[tid] = 0;  // ws is poisoned

    float acc = 0.0f;
    // ---- pass 1: row-run labels via ballot (wave w handles rows r%8==w) ----
#pragma unroll
    for (int j = 0; j < 8; j++) {
        int row = wave + j * 8;
        float p = pi[baseLocal + row * IMG_W + lane];
        acc += fmaxf(__logf(1.0f - p), -100.0f);   // 1-p exact for p>=0.5
        bool fg = (p >= 0.5f);
        unsigned long long bal = __ballot(fg);
        unsigned long long starts = bal & ~(bal << 1);
        unsigned long long maskle =
            (lane == 63) ? ~0ULL : ((1ULL << (lane + 1)) - 1ULL);
        int lb = -1;
        if (fg) {
            unsigned long long pre = starts & maskle;   // nonzero when fg
            lb = row * TILE + (63 - __builtin_clzll(pre));
        }
        lab[row * TILE + lane] = lb;
    }
    __syncthreads();
    // ---- pass 2: vertical unites, one per contact-run ----------------------
#pragma unroll
    for (int j = 0; j < 8; j++) {
        int row = wave + j * 8;
        if (row == 0) continue;                   // wave-uniform
        int i = row * TILE + lane;
        bool c = (lab[i] >= 0) && (lab[i - TILE] >= 0);
        unsigned long long cb = __ballot(c);
        unsigned long long cs = cb & ~(cb << 1);  // first lane of each contact
        if ((cs >> lane) & 1ULL) uf_unite(lab, i, i - TILE);
    }
    __syncthreads();
    // ---- pass 3a: run-starts chase to root + sparse root export ------------
    int* rl = rootList + (size_t)tile * RTSTRIDE;
#pragma unroll
    for (int j = 0; j < 8; j++) {
        int row = wave + j * 8;
        int i = row * TILE + lane;
        bool fg = (lab[i] >= 0);
        unsigned long long bal = __ballot(fg);
        unsigned long long st = bal & ~(bal << 1);
        if ((st >> lane) & 1ULL) {
            int x = i, p = lab[x];
            while (p != x) {
                int g = lab[p];
                lab[x] = g;          // halving: benign race, ancestors only
                x = g;
                p = lab[x];
            }
            lab[i] = x;              // full compress for the start entry
            if (x == i) {            // i is a LOCAL ROOT (~270/tile)
                int b = atomicAdd(&rootc, 1);
                rl[b] = baseLocal + (i >> 6) * IMG_W + (i & 63);
            }
        }
    }
    __syncthreads();
    // ---- pass 3b: b128 gather + global write (int4) ------------------------
#pragma unroll
    for (int j = 0; j < 2; j++) {
        int i4 = (tid + j * 512) * 4;
        int4 s4 = *(const int4*)&lab[i4];        // one ds_read_b128
        const int* sp = (const int*)&s4;
        int4 o;
        int* op = (int*)&o;
#pragma unroll
        for (int k = 0; k < 4; k++) {
            int s = sp[k];
            if (s < 0) op[k] = -1;
            else {
                int r = lab[s];                  // root (starts compressed)
                op[k] = baseLocal + (r >> 6) * IMG_W + (r & 63);
            }
        }
        *(int4*)(Li + baseLocal + (i4 >> 6) * IMG_W + (i4 & 63)) = o;
    }
    // ---- edge export: 4 x 64 labels, coalesced -----------------------------
    if (tid < 256) {
        int e = tid >> 6;                        // 0=T,1=B,2=L,3=R
        int q = tid & 63;
        int px = (e == 0) ? q
               : (e == 1) ? (63 * TILE + q)
               : (e == 2) ? (q * TILE)
               :            (q * TILE + 63);
        int s = lab[px];
        int val = -1;
        if (s >= 0) {
            int r = lab[s];
            val = baseLocal + (r >> 6) * IMG_W + (r & 63);
        }
        edges[e * EDGE_N + tile * 64 + q] = val;
    }
    // ---- base BCE: wave shuffle reduce (1 barrier) -------------------------
#pragma unroll
    for (int o = 32; o > 0; o >>= 1) acc += __shfl_down(acc, o);
    if (lane == 0) swf[wave] = acc;
    __syncthreads();                             // also orders rootc/rl
    if (tid == 0) {
        float s = 0.0f;
#pragma unroll
        for (int w = 0; w < 8; w++) s += swf[w];
        partials[blockIdx.x] = s;
        rootCnt[tile] = rootc;
        if (blockIdx.x == 0) *counter = 0u;      // ws is 0xAA-poisoned
    }
}

// ---------------- K2: cross-tile border unites + demotion export ------------
// One wave per tile-pair (3584 waves, full TLP). Each successful unite
// demotes exactly one root; export it to the image's compact demList
// (one wave-aggregated atomicAdd, ~900 entries/img total).
__global__ __launch_bounds__(256) void k_border(const int* __restrict__ edges,
                                                int* __restrict__ L,
                                                int* __restrict__ demCnt,
                                                int* __restrict__ demList) {
    int gid = blockIdx.x * blockDim.x + threadIdx.x;
    int pair = gid >> 6;                 // wave-uniform
    int lane = gid & 63;
    int a, b, img;
    if (pair < NIMG * 56) {              // vertical: (ty,tx)-(ty,tx+1)
        img = pair / 56;
        int w = pair - img * 56;
        int ty = w / 7, tx = w - ty * 7;
        int tl = img * TPI + ty * 8 + tx;
        a = edges[3 * EDGE_N + tl * 64 + lane];        // right edge of left
        b = edges[2 * EDGE_N + (tl + 1) * 64 + lane];  // left edge of right
    } else {                             // horizontal: (ty,tx)-(ty+1,tx)
        int p2 = pair - NIMG * 56;
        img = p2 / 56;
        int w = p2 - img * 56;
        int ty = w >> 3, tx = w & 7;
        int tu = img * TPI + ty * 8 + tx;
        a = edges[1 * EDGE_N + tu * 64 + lane];        // bottom edge of upper
        b = edges[0 * EDGE_N + (tu + 8) * 64 + lane];  // top edge of lower
    }
    bool c = (a >= 0) && (b >= 0);
    unsigned long long cb = __ballot(c);
    unsigned long long cs = cb & ~(cb << 1);           // contact-run starts
    int d = -1;
    if ((cs >> lane) & 1ULL)
        d = uf_unite_dem(L + ((size_t)img << LOGHW), a, b);
    // ---- wave-aggregated demotion export (img is wave-uniform) -------------
    unsigned long long db = __ballot(d >= 0);
    if (db) {
        int leader = __ffsll(db) - 1;
        int base = 0;
        if (lane == leader) base = atomicAdd(&demCnt[img], __popcll(db));
        base = __shfl(base, leader);
        if (d >= 0) {
            int rank = __popcll(db & ((1ULL << lane) - 1ULL));
            demList[img * DEMCAP + base + rank] = d;
        }
    }
}

// ---------------- K3: demotion-bitmap stats + rv + final reduce -------------
// One block (512 thr) per image. Surviving roots = local roots \ demoted.
// num = sum(rootCnt) - demCnt (exact); last_root = max non-demoted local root
// via 32KB LDS bitmap + coalesced rootList scan. No scattered global probes.
// v = last_root if >=1; else lazy minFg scan / 1. rv >= 0 (v<=num, never on
// this input) falls back to in-block full-L selection + correction scan.
// Last of the 32 blocks (32-way counter — the only safe handshake pattern)
// reduces k_local's 2048 base partials + 32 corrections.
__global__ __launch_bounds__(512) void k_tail(const int* __restrict__ rootCnt,
                                              const int* __restrict__ rootList,
                                              const int* __restrict__ demCnt,
                                              const int* __restrict__ demList,
                                              const int* __restrict__ L,
                                              const float* __restrict__ pred,
                                              const float* __restrict__ partials,
                                              float* __restrict__ corr,
                                              unsigned int* __restrict__ counter,
                                              float* __restrict__ out) {
    __shared__ unsigned bm[HW / 32];     // 32 KB demoted-root bitmap
    __shared__ int pre[65];              // inclusive prefix of 64 tile counts
    __shared__ int sc[512], sm[512];
    __shared__ int result;
    __shared__ float sf[512];
    __shared__ double sd[512];
    __shared__ unsigned int oldc;
    int img = blockIdx.x, t = threadIdx.x;
    const int* Li = L + ((size_t)img << LOGHW);

    for (int i = t; i < HW / 32; i += 512) bm[i] = 0u;
    if (t < 64) {                        // wave-0 shuffle scan of tile counts
        int v = rootCnt[img * TPI + t];
#pragma unroll
        for (int o = 1; o < 64; o <<= 1) {
            int u = __shfl_up(v, o);
            if (t >= o) v += u;
        }
        pre[t + 1] = v;
        if (t == 0) pre[0] = 0;
    }
    if (t == 0) result = -2;
    __syncthreads();
    int C = pre[64];                     // total local roots (~18K)
    int D = demCnt[img];                 // demotions (~900)
    for (int k = t; k < D; k += 512) {   // build bitmap (scattered LDS, cheap)
        int d = demList[img * DEMCAP + k];
        atomicOr(&bm[d >> 5], 1u << (d & 31));
    }
    __syncthreads();
    // ---- coalesced rootList scan: max surviving root -----------------------
    int tt = t >> 3, j0 = t & 7;         // 8 threads per tile
    int rc = pre[tt + 1] - pre[tt];
    const int* rl = rootList + (size_t)(img * TPI + tt) * RTSTRIDE;
    int mx = -1;
    for (int k = j0; k < rc; k += 8) {
        int r = rl[k];
        if (!((bm[r >> 5] >> (r & 31)) & 1u)) mx = max(mx, r);
    }
    sm[t] = mx;
    __syncthreads();
    for (int s = 256; s > 0; s >>= 1) {
        if (t < s) sm[t] = max(sm[t], sm[t + s]);
        __syncthreads();
    }
    int num = C - D, last_root = sm[0];
    int v;
    if (last_root >= 1) {                // block-uniform (common case)
        v = last_root;
    } else {
        // rare: lazy minFg = first fg index >= 1 (coalesced Li scan)
        __syncthreads();                 // sc reuse
        int mn = HW;
        for (int i0 = t * 4; i0 < HW; i0 += 2048) {
            int4 l4 = *(const int4*)(Li + i0);
            if (l4.x >= 0 && i0 >= 1) mn = min(mn, i0);
            if (l4.y >= 0) mn = min(mn, i0 + 1);
            if (l4.z >= 0) mn = min(mn, i0 + 2);
            if (l4.w >= 0) mn = min(mn, i0 + 3);
        }
        sc[t] = mn;
        __syncthreads();
        for (int s = 256; s > 0; s >>= 1) {
            if (t < s) sc[t] = min(sc[t], sc[t + s]);
            __syncthreads();
        }
        mn = sc[0];
        v = (last_root == 0) ? ((mn < HW) ? mn : 1) : 1;
        __syncthreads();
    }

    // ---- rare path: select v-th surviving root in raster order -------------
    if (v >= 1 && v <= num) {            // block-uniform branch
        __syncthreads();                 // sc reuse
        int base = t * (HW / 512);       // contiguous 512-px raster range
        int c = 0;
        for (int j = 0; j < 128; j++) {
            int off = base + j * 4;
            int4 l4 = *(const int4*)(Li + off);
            c += (l4.x == off) + (l4.y == off + 1)
               + (l4.z == off + 2) + (l4.w == off + 3);
        }
        sc[t] = c;
        __syncthreads();
        for (int off = 1; off < 512; off <<= 1) {
            int v2 = (t >= off) ? sc[t - off] : 0;
            __syncthreads();
            sc[t] += v2;
            __syncthreads();
        }
        int inc = sc[t], exc = inc - c;
        if (exc < v && v <= inc) {       // my range holds the v-th root
            int need = v - exc, run = 0;
            for (int j = 0; j < 128; j++) {
                int off = base + j * 4;
                int4 l4 = *(const int4*)(Li + off);
                if (l4.x == off)     { run++; if (run == need) result = off; }
                if (l4.y == off + 1) { run++; if (run == need) result = off + 1; }
                if (l4.z == off + 2) { run++; if (run == need) result = off + 2; }
                if (l4.w == off + 3) { run++; if (run == need) result = off + 3; }
                if (run >= need) break;
            }
        }
        __syncthreads();
    }
    int rvv = result;
    float blocksum = 0.0f;
    if (rvv >= 0) {                      // rare path: scan whole image
        const float* pi = pred + ((size_t)img << LOGHW);
        float acc = 0.0f;
        for (int it = 0; it < HW / 2048; it++) {
            int off = it * 2048 + t * 4;
            float4 p4 = *(const float4*)(pi + off);
            int4 l4 = *(const int4*)(Li + off);
            const float* pp = (const float*)&p4;
            const int* lp = (const int*)&l4;
#pragma unroll
            for (int k = 0; k < 4; k++) {
                int p = lp[k];
                if (p < 0) continue;
                int x = p, q = Li[x];
                while (q != x) { x = q; q = Li[x]; }
                if (x == rvv) {
                    float pr = pp[k];
                    acc += fmaxf(__logf(pr), -100.0f)
                         - fmaxf(__logf(1.0f - pr), -100.0f);
                }
            }
        }
        sf[t] = acc;
        __syncthreads();
        for (int s = 256; s > 0; s >>= 1) {
            if (t < s) sf[t] += sf[t + s];
            __syncthreads();
        }
        blocksum = sf[0];
    }
    if (t == 0) {
        __hip_atomic_store(&corr[img], blocksum, __ATOMIC_RELAXED,
                           __HIP_MEMORY_SCOPE_AGENT);
        oldc = __hip_atomic_fetch_add(counter, 1u, __ATOMIC_ACQ_REL,
                                      __HIP_MEMORY_SCOPE_AGENT);
    }
    __syncthreads();
    if (oldc != NIMG - 1) return;
    // ---- last of 32 blocks: final reduce -----------------------------------
    double acc = 0.0;
#pragma unroll
    for (int j = 0; j < 4; j++) acc += (double)partials[t + j * 512];
    if (t < NIMG)
        acc += (double)__hip_atomic_load(&corr[t], __ATOMIC_ACQUIRE,
                                         __HIP_MEMORY_SCOPE_AGENT);
    sd[t] = acc;
    __syncthreads();
    for (int s = 256; s > 0; s >>= 1) {
        if (t < s) sd[t] += sd[t + s];
        __syncthreads();
    }
    if (t == 0) out[0] = (float)(-sd[0] / (double)NTOT);
}

extern "C" void kernel_launch(void* const* d_in, const int* in_sizes, int n_in,
                              void* d_out, int out_size, void* d_ws, size_t ws_size,
                              hipStream_t stream) {
    const float* pred = (const float*)d_in[0];
    float* out = (float*)d_out;

    char* ws = (char*)d_ws;
    int* L = (int*)ws;                                        // 33.5 MB
    int* edges = (int*)(ws + (size_t)NTOT * 4);               // 2 MB (4 dirs)
    int* rootList = edges + 4 * EDGE_N;                       // 16.8 MB
    int* rootCnt = rootList + (size_t)NTILE * RTSTRIDE;       // 8 KB
    int* demCnt = rootCnt + NTILE;                            // 128 B
    int* demList = demCnt + NIMG;                             // 512 KB
    float* partials = (float*)(demList + NIMG * DEMCAP);      // 8 KB
    float* corr = partials + NTILE;                           // 128 B
    unsigned int* counter = (unsigned int*)(corr + NIMG);     // 4 B

    k_local<<<dim3(NTILE), dim3(512), 0, stream>>>(pred, L, partials, edges,
                                                   rootCnt, rootList, demCnt,
                                                   counter);
    k_border<<<dim3(NPAIR * 64 / 256), dim3(256), 0, stream>>>(edges, L,
                                                               demCnt, demList);
    k_tail<<<dim3(NIMG), dim3(512), 0, stream>>>(rootCnt, rootList, demCnt,
                                                 demList, L, pred, partials,
                                                 corr, counter, out);
}

// Round 4
// 129.250 us; speedup vs baseline: 1.1302x; 1.1302x over previous
//
#include <hip/hip_runtime.h>
#include <math.h>

// Problem constants (fixed by reference setup_inputs): pred [32,1,512,512] f32
#define IMG_W 512
#define IMG_H 512
#define HW (IMG_W * IMG_H)      // 262144 = 2^18
#define LOGHW 18
#define NIMG 32
#define NTOT (NIMG * HW)        // 8388608
#define TILE 64
#define TPI 64                  // 8x8 tiles of 64x64 per image
#define NTILE (NIMG * TPI)      // 2048
#define EDGE_N (NTILE * 64)     // 131072 entries per edge direction
#define PPI 112                 // tile-pairs per image (56 vert + 56 horiz)
#define NPAIR (NIMG * PPI)      // 3584
#define RTSTRIDE 2048           // max roots per 64x64 tile (checkerboard bound)
// NOTE (R6/R15/R18): NO contended device-scope atomics. R6: 2048-way single
// counter = 56us (~27ns per serialized RMW). R18: 3584 wave atomicAdds onto
// demCnt[32] (2 cache lines!) = ~25us line-granular serialization. Fix here:
// per-pair fixed 64-slot segments, unconditional coalesced stores, ZERO
// atomics. 32-way counter in the 32-block k_tail grid is the only safe
// handshake pattern.
// NOTE (R12): no big register prefetch in k_local — occupancy > prefetch.
// NOTE (R8..R14): k_local latency floor ~42-46us; harness fixed cost ~55us
// in-window (256MiB ws poison fill = 44us at HBM ceiling — untouchable).
// NOTE (R16/R17): scattered per-candidate global probes in a 32-block k_tail
// are dependent-latency serialized (~1.5us/K candidates); per-pixel VALU in
// k_local's hot passes costs +6us. Export sparse data from diverged paths
// only; NEVER probe — count.
// R18/R19 scheme: a root is demoted exactly once (successful atomicMin with
// old==a). num = sumLocalRoots - demotions; last_root = max rootList entry
// not in the demoted bitmap. Coalesced reads only.

// ---------------- lock-free min-index union-find ----------------------------
__device__ __forceinline__ void uf_unite(int* L, int a, int b) {
    while (true) {
        int p = ((volatile int*)L)[a];
        while (p != a) { a = p; p = ((volatile int*)L)[a]; }
        p = ((volatile int*)L)[b];
        while (p != b) { b = p; p = ((volatile int*)L)[b]; }
        if (a == b) return;
        if (a < b) { int t = a; a = b; b = t; }  // a > b
        int old = atomicMin(&L[a], b);
        if (old == a) return;
        a = old;
    }
}

// Variant returning the demoted root (-1 if the two were already united).
// Parent pointers only decrease and L[x] <= x always, so L[a]==a can flip to
// L[a]<a exactly once per index a, and only via the old==a success below.
__device__ __forceinline__ int uf_unite_dem(int* L, int a, int b) {
    while (true) {
        int p = ((volatile int*)L)[a];
        while (p != a) { a = p; p = ((volatile int*)L)[a]; }
        p = ((volatile int*)L)[b];
        while (p != b) { b = p; p = ((volatile int*)L)[b]; }
        if (a == b) return -1;
        if (a < b) { int t = a; a = b; b = t; }  // a > b
        int old = atomicMin(&L[a], b);
        if (old == a) return a;                  // root a demoted (unique)
        a = old;
    }
}

// ---------------- K1: CCL + base BCE + edge export + root-list export -------
// One block (512 thr, 8 waves) per 64x64 tile; row width == wave width.
// Pass 1: row-run labels via ballot + fused base BCE sum.
// Pass 2: vertical unites only at contact-run starts (~750/tile).
// Pass 3a: run-starts chase to root; roots (x==i, ~270/tile) append their
//   image-local index to this tile's rootList segment (LDS counter, sparse).
// Pass 3b: every px root = lab[lab[px]] (b128 read + gather); write global L.
__global__ __launch_bounds__(512) void k_local(const float* __restrict__ pred,
                                               int* __restrict__ L,
                                               float* __restrict__ partials,
                                               int* __restrict__ edges,
                                               int* __restrict__ rootCnt,
                                               int* __restrict__ rootList,
                                               unsigned int* __restrict__ counter) {
    __shared__ int lab[TILE * TILE];   // 16 KB
    __shared__ float swf[8];
    __shared__ int rootc;
    int tile = blockIdx.x;
    int img = tile >> 6;
    int t = tile & (TPI - 1);
    int ty = t >> 3, tx = t & 7;
    int baseLocal = (ty * TILE) * IMG_W + tx * TILE;  // image-local origin
    const float* pi = pred + ((size_t)img << LOGHW);
    int* Li = L + ((size_t)img << LOGHW);
    int tid = threadIdx.x;
    int lane = tid & 63, wave = tid >> 6;             // wave 0..7
    if (tid == 0) rootc = 0;

    float acc = 0.0f;
    // ---- pass 1: row-run labels via ballot (wave w handles rows r%8==w) ----
#pragma unroll
    for (int j = 0; j < 8; j++) {
        int row = wave + j * 8;
        float p = pi[baseLocal + row * IMG_W + lane];
        acc += fmaxf(__logf(1.0f - p), -100.0f);   // 1-p exact for p>=0.5
        bool fg = (p >= 0.5f);
        unsigned long long bal = __ballot(fg);
        unsigned long long starts = bal & ~(bal << 1);
        unsigned long long maskle =
            (lane == 63) ? ~0ULL : ((1ULL << (lane + 1)) - 1ULL);
        int lb = -1;
        if (fg) {
            unsigned long long pre = starts & maskle;   // nonzero when fg
            lb = row * TILE + (63 - __builtin_clzll(pre));
        }
        lab[row * TILE + lane] = lb;
    }
    __syncthreads();
    // ---- pass 2: vertical unites, one per contact-run ----------------------
#pragma unroll
    for (int j = 0; j < 8; j++) {
        int row = wave + j * 8;
        if (row == 0) continue;                   // wave-uniform
        int i = row * TILE + lane;
        bool c = (lab[i] >= 0) && (lab[i - TILE] >= 0);
        unsigned long long cb = __ballot(c);
        unsigned long long cs = cb & ~(cb << 1);  // first lane of each contact
        if ((cs >> lane) & 1ULL) uf_unite(lab, i, i - TILE);
    }
    __syncthreads();
    // ---- pass 3a: run-starts chase to root + sparse root export ------------
    int* rl = rootList + (size_t)tile * RTSTRIDE;
#pragma unroll
    for (int j = 0; j < 8; j++) {
        int row = wave + j * 8;
        int i = row * TILE + lane;
        bool fg = (lab[i] >= 0);
        unsigned long long bal = __ballot(fg);
        unsigned long long st = bal & ~(bal << 1);
        if ((st >> lane) & 1ULL) {
            int x = i, p = lab[x];
            while (p != x) {
                int g = lab[p];
                lab[x] = g;          // halving: benign race, ancestors only
                x = g;
                p = lab[x];
            }
            lab[i] = x;              // full compress for the start entry
            if (x == i) {            // i is a LOCAL ROOT (~270/tile)
                int b = atomicAdd(&rootc, 1);   // LDS atomic (per-block, safe)
                rl[b] = baseLocal + (i >> 6) * IMG_W + (i & 63);
            }
        }
    }
    __syncthreads();
    // ---- pass 3b: b128 gather + global write (int4) ------------------------
#pragma unroll
    for (int j = 0; j < 2; j++) {
        int i4 = (tid + j * 512) * 4;
        int4 s4 = *(const int4*)&lab[i4];        // one ds_read_b128
        const int* sp = (const int*)&s4;
        int4 o;
        int* op = (int*)&o;
#pragma unroll
        for (int k = 0; k < 4; k++) {
            int s = sp[k];
            if (s < 0) op[k] = -1;
            else {
                int r = lab[s];                  // root (starts compressed)
                op[k] = baseLocal + (r >> 6) * IMG_W + (r & 63);
            }
        }
        *(int4*)(Li + baseLocal + (i4 >> 6) * IMG_W + (i4 & 63)) = o;
    }
    // ---- edge export: 4 x 64 labels, coalesced -----------------------------
    if (tid < 256) {
        int e = tid >> 6;                        // 0=T,1=B,2=L,3=R
        int q = tid & 63;
        int px = (e == 0) ? q
               : (e == 1) ? (63 * TILE + q)
               : (e == 2) ? (q * TILE)
               :            (q * TILE + 63);
        int s = lab[px];
        int val = -1;
        if (s >= 0) {
            int r = lab[s];
            val = baseLocal + (r >> 6) * IMG_W + (r & 63);
        }
        edges[e * EDGE_N + tile * 64 + q] = val;
    }
    // ---- base BCE: wave shuffle reduce (1 barrier) -------------------------
#pragma unroll
    for (int o = 32; o > 0; o >>= 1) acc += __shfl_down(acc, o);
    if (lane == 0) swf[wave] = acc;
    __syncthreads();                             // also orders rootc/rl
    if (tid == 0) {
        float s = 0.0f;
#pragma unroll
        for (int w = 0; w < 8; w++) s += swf[w];
        partials[blockIdx.x] = s;
        rootCnt[tile] = rootc;
        if (blockIdx.x == 0) *counter = 0u;      // ws is 0xAA-poisoned
    }
}

// ---------------- K2: cross-tile border unites + demotion export ------------
// One wave per tile-pair (3584 waves, full TLP). Each successful unite
// demotes exactly one root. Export: every lane stores its result (-1 if none)
// to its pair's fixed 64-slot segment — fully coalesced, ZERO atomics, no
// init needed (every slot written every run). (R18 lesson: wave atomicAdds
// onto a 2-cache-line counter array cost ~25us of line serialization.)
__global__ __launch_bounds__(256) void k_border(const int* __restrict__ edges,
                                                int* __restrict__ L,
                                                int* __restrict__ demList) {
    int gid = blockIdx.x * blockDim.x + threadIdx.x;
    int pair = gid >> 6;                 // wave-uniform
    int lane = gid & 63;
    int a, b, img;
    if (pair < NIMG * 56) {              // vertical: (ty,tx)-(ty,tx+1)
        img = pair / 56;
        int w = pair - img * 56;
        int ty = w / 7, tx = w - ty * 7;
        int tl = img * TPI + ty * 8 + tx;
        a = edges[3 * EDGE_N + tl * 64 + lane];        // right edge of left
        b = edges[2 * EDGE_N + (tl + 1) * 64 + lane];  // left edge of right
    } else {                             // horizontal: (ty,tx)-(ty+1,tx)
        int p2 = pair - NIMG * 56;
        img = p2 / 56;
        int w = p2 - img * 56;
        int ty = w >> 3, tx = w & 7;
        int tu = img * TPI + ty * 8 + tx;
        a = edges[1 * EDGE_N + tu * 64 + lane];        // bottom edge of upper
        b = edges[0 * EDGE_N + (tu + 8) * 64 + lane];  // top edge of lower
    }
    bool c = (a >= 0) && (b >= 0);
    unsigned long long cb = __ballot(c);
    unsigned long long cs = cb & ~(cb << 1);           // contact-run starts
    int d = -1;
    if ((cs >> lane) & 1ULL)
        d = uf_unite_dem(L + ((size_t)img << LOGHW), a, b);
    demList[pair * 64 + lane] = d;       // coalesced, unconditional, no atomics
}

// ---------------- K3: demotion-bitmap stats + rv + final reduce -------------
// One block (512 thr) per image. Surviving roots = local roots \ demoted.
// num = sum(rootCnt) - D (exact); last_root = max non-demoted local root via
// 32KB LDS bitmap + coalesced rootList scan. No scattered global probes, no
// contended atomics. v = last_root if >=1; else lazy minFg scan / 1. rv >= 0
// (v<=num, never on this input) falls back to in-block full-L selection +
// correction scan. Last of the 32 blocks (32-way counter — the only safe
// handshake pattern) reduces k_local's 2048 base partials + 32 corrections.
__global__ __launch_bounds__(512) void k_tail(const int* __restrict__ rootCnt,
                                              const int* __restrict__ rootList,
                                              const int* __restrict__ demList,
                                              const int* __restrict__ L,
                                              const float* __restrict__ pred,
                                              const float* __restrict__ partials,
                                              float* __restrict__ corr,
                                              unsigned int* __restrict__ counter,
                                              float* __restrict__ out) {
    __shared__ unsigned bm[HW / 32];     // 32 KB demoted-root bitmap
    __shared__ int pre[65];              // inclusive prefix of 64 tile counts
    __shared__ int sc[512], sm[512];
    __shared__ int result;
    __shared__ float sf[512];
    __shared__ double sd[512];
    __shared__ unsigned int oldc;
    int img = blockIdx.x, t = threadIdx.x;
    const int* Li = L + ((size_t)img << LOGHW);

    for (int i = t; i < HW / 32; i += 512) bm[i] = 0u;
    if (t < 64) {                        // wave-0 shuffle scan of tile counts
        int v = rootCnt[img * TPI + t];
#pragma unroll
        for (int o = 1; o < 64; o <<= 1) {
            int u = __shfl_up(v, o);
            if (t >= o) v += u;
        }
        pre[t + 1] = v;
        if (t == 0) pre[0] = 0;
    }
    if (t == 0) result = -2;
    __syncthreads();
    int C = pre[64];                     // total local roots (~18K)
    // ---- demotion segments: 112 pairs x 64 slots, coalesced ----------------
    int dcnt = 0;
#pragma unroll
    for (int s = t; s < PPI * 64; s += 512) {   // 14 iterations
        int w = s >> 6, ln = s & 63;
        int pr = (w < 56) ? (img * 56 + w)
                          : (NIMG * 56 + img * 56 + (w - 56));
        int d = demList[pr * 64 + ln];
        if (d >= 0) {
            dcnt++;
            atomicOr(&bm[d >> 5], 1u << (d & 31));   // LDS atomic (cheap)
        }
    }
    __syncthreads();
    // ---- coalesced rootList scan: max surviving root -----------------------
    int tt = t >> 3, j0 = t & 7;         // 8 threads per tile
    int rc = pre[tt + 1] - pre[tt];
    const int* rl = rootList + (size_t)(img * TPI + tt) * RTSTRIDE;
    int mx = -1;
    for (int k = j0; k < rc; k += 8) {
        int r = rl[k];
        if (!((bm[r >> 5] >> (r & 31)) & 1u)) mx = max(mx, r);
    }
    sc[t] = dcnt; sm[t] = mx;
    __syncthreads();
    for (int s = 256; s > 0; s >>= 1) {
        if (t < s) { sc[t] += sc[t + s]; sm[t] = max(sm[t], sm[t + s]); }
        __syncthreads();
    }
    int num = C - sc[0], last_root = sm[0];
    int v;
    if (last_root >= 1) {                // block-uniform (common case)
        v = last_root;
    } else {
        // rare: lazy minFg = first fg index >= 1 (coalesced Li scan)
        __syncthreads();                 // sc reuse
        int mn = HW;
        for (int i0 = t * 4; i0 < HW; i0 += 2048) {
            int4 l4 = *(const int4*)(Li + i0);
            if (l4.x >= 0 && i0 >= 1) mn = min(mn, i0);
            if (l4.y >= 0) mn = min(mn, i0 + 1);
            if (l4.z >= 0) mn = min(mn, i0 + 2);
            if (l4.w >= 0) mn = min(mn, i0 + 3);
        }
        sc[t] = mn;
        __syncthreads();
        for (int s = 256; s > 0; s >>= 1) {
            if (t < s) sc[t] = min(sc[t], sc[t + s]);
            __syncthreads();
        }
        mn = sc[0];
        v = (last_root == 0) ? ((mn < HW) ? mn : 1) : 1;
        __syncthreads();
    }

    // ---- rare path: select v-th surviving root in raster order -------------
    if (v >= 1 && v <= num) {            // block-uniform branch
        __syncthreads();                 // sc reuse
        int base = t * (HW / 512);       // contiguous 512-px raster range
        int c = 0;
        for (int j = 0; j < 128; j++) {
            int off = base + j * 4;
            int4 l4 = *(const int4*)(Li + off);
            c += (l4.x == off) + (l4.y == off + 1)
               + (l4.z == off + 2) + (l4.w == off + 3);
        }
        sc[t] = c;
        __syncthreads();
        for (int off = 1; off < 512; off <<= 1) {
            int v2 = (t >= off) ? sc[t - off] : 0;
            __syncthreads();
            sc[t] += v2;
            __syncthreads();
        }
        int inc = sc[t], exc = inc - c;
        if (exc < v && v <= inc) {       // my range holds the v-th root
            int need = v - exc, run = 0;
            for (int j = 0; j < 128; j++) {
                int off = base + j * 4;
                int4 l4 = *(const int4*)(Li + off);
                if (l4.x == off)     { run++; if (run == need) result = off; }
                if (l4.y == off + 1) { run++; if (run == need) result = off + 1; }
                if (l4.z == off + 2) { run++; if (run == need) result = off + 2; }
                if (l4.w == off + 3) { run++; if (run == need) result = off + 3; }
                if (run >= need) break;
            }
        }
        __syncthreads();
    }
    int rvv = result;
    float blocksum = 0.0f;
    if (rvv >= 0) {                      // rare path: scan whole image
        const float* pi = pred + ((size_t)img << LOGHW);
        float acc = 0.0f;
        for (int it = 0; it < HW / 2048; it++) {
            int off = it * 2048 + t * 4;
            float4 p4 = *(const float4*)(pi + off);
            int4 l4 = *(const int4*)(Li + off);
            const float* pp = (const float*)&p4;
            const int* lp = (const int*)&l4;
#pragma unroll
            for (int k = 0; k < 4; k++) {
                int p = lp[k];
                if (p < 0) continue;
                int x = p, q = Li[x];
                while (q != x) { x = q; q = Li[x]; }
                if (x == rvv) {
                    float pr = pp[k];
                    acc += fmaxf(__logf(pr), -100.0f)
                         - fmaxf(__logf(1.0f - pr), -100.0f);
                }
            }
        }
        sf[t] = acc;
        __syncthreads();
        for (int s = 256; s > 0; s >>= 1) {
            if (t < s) sf[t] += sf[t + s];
            __syncthreads();
        }
        blocksum = sf[0];
    }
    if (t == 0) {
        __hip_atomic_store(&corr[img], blocksum, __ATOMIC_RELAXED,
                           __HIP_MEMORY_SCOPE_AGENT);
        oldc = __hip_atomic_fetch_add(counter, 1u, __ATOMIC_ACQ_REL,
                                      __HIP_MEMORY_SCOPE_AGENT);
    }
    __syncthreads();
    if (oldc != NIMG - 1) return;
    // ---- last of 32 blocks: final reduce -----------------------------------
    double acc = 0.0;
#pragma unroll
    for (int j = 0; j < 4; j++) acc += (double)partials[t + j * 512];
    if (t < NIMG)
        acc += (double)__hip_atomic_load(&corr[t], __ATOMIC_ACQUIRE,
                                         __HIP_MEMORY_SCOPE_AGENT);
    sd[t] = acc;
    __syncthreads();
    for (int s = 256; s > 0; s >>= 1) {
        if (t < s) sd[t] += sd[t + s];
        __syncthreads();
    }
    if (t == 0) out[0] = (float)(-sd[0] / (double)NTOT);
}

extern "C" void kernel_launch(void* const* d_in, const int* in_sizes, int n_in,
                              void* d_out, int out_size, void* d_ws, size_t ws_size,
                              hipStream_t stream) {
    const float* pred = (const float*)d_in[0];
    float* out = (float*)d_out;

    char* ws = (char*)d_ws;
    int* L = (int*)ws;                                        // 33.5 MB
    int* edges = (int*)(ws + (size_t)NTOT * 4);               // 2 MB (4 dirs)
    int* rootList = edges + 4 * EDGE_N;                       // 16.8 MB
    int* rootCnt = rootList + (size_t)NTILE * RTSTRIDE;       // 8 KB
    int* demList = rootCnt + NTILE;                           // 896 KB
    float* partials = (float*)(demList + NPAIR * 64);         // 8 KB
    float* corr = partials + NTILE;                           // 128 B
    unsigned int* counter = (unsigned int*)(corr + NIMG);     // 4 B

    k_local<<<dim3(NTILE), dim3(512), 0, stream>>>(pred, L, partials, edges,
                                                   rootCnt, rootList, counter);
    k_border<<<dim3(NPAIR * 64 / 256), dim3(256), 0, stream>>>(edges, L,
                                                               demList);
    k_tail<<<dim3(NIMG), dim3(512), 0, stream>>>(rootCnt, rootList, demList,
                                                 L, pred, partials, corr,
                                                 counter, out);
}

// Round 5
// 121.247 us; speedup vs baseline: 1.2048x; 1.0660x over previous
//
#include <hip/hip_runtime.h>
#include <math.h>

// Problem constants (fixed by reference setup_inputs): pred [32,1,512,512] f32
#define IMG_W 512
#define IMG_H 512
#define HW (IMG_W * IMG_H)      // 262144 = 2^18
#define LOGHW 18
#define NIMG 32
#define NTOT (NIMG * HW)        // 8388608
#define TILE 64
#define TPI 64                  // 8x8 tiles of 64x64 per image
#define NTILE (NIMG * TPI)      // 2048
#define EDGE_N (NTILE * 64)     // 131072 entries per edge direction
#define NPAIR (NIMG * 112)      // 56 vertical + 56 horizontal tile-pairs/img
#define RTSTRIDE 2048           // max roots per 64x64 tile (checkerboard bound)
// LESSON LEDGER:
// R6/R15/R18: NO contended device-scope atomics (2048-way counter = 56us;
//   3584 wave atomicAdds onto a 2-line counter array = ~25us). The 32-way
//   counter in the 32-block k_tail grid is the only safe handshake.
// R12: no big register prefetch in k_local — occupancy > prefetch.
// R8..R14: k_local latency floor ~42-46us; harness fixed cost ~55us in-window
//   (256MiB ws poison fill = 44us at HBM ceiling — untouchable).
// R16/R17/R19: ANY non-trivial memory loop in the 32-block k_tail is
//   latency-bound (1 wave/CU, zero TLP): ~15-25us. The same bytes in a
//   2048-block grid are bandwidth-bound: ~3-6us. Put memory loops where the
//   TLP is; k_tail may only do O(64) reads + reductions.
// R20: global roots are a subset of k_local's local roots (unites only
//   demote). k_probe (one wave per tile, 2048 blocks) tests L[r]==r over the
//   tile's ~270 exported local roots -> cntT/maxT per tile. k_tail reduces
//   64 values per image. Replaces baseline k_stats's full 33.5MB L re-read.

// ---------------- lock-free min-index union-find ----------------------------
__device__ __forceinline__ void uf_unite(int* L, int a, int b) {
    while (true) {
        // find roots (reads may be stale -> only costs retries, never wrong)
        int p = ((volatile int*)L)[a];
        while (p != a) { a = p; p = ((volatile int*)L)[a]; }
        p = ((volatile int*)L)[b];
        while (p != b) { b = p; p = ((volatile int*)L)[b]; }
        if (a == b) return;
        if (a < b) { int t = a; a = b; b = t; }  // a > b
        int old = atomicMin(&L[a], b);
        if (old == a) return;
        a = old;
    }
}

// ---------------- K1: CCL + base BCE + edge export + root-list export -------
// One block (512 thr, 8 waves) per 64x64 tile; row width == wave width.
// Pass 1: row-run labels via ballot + fused base BCE sum.
// Pass 2: vertical unites only at contact-run starts (~750/tile).
// Pass 3a: run-starts chase to root; roots (x==i, ~270/tile) append their
//   image-local index to this tile's rootList segment (LDS counter, sparse).
// Pass 3b: every px root = lab[lab[px]] (b128 read + gather); write global L.
__global__ __launch_bounds__(512) void k_local(const float* __restrict__ pred,
                                               int* __restrict__ L,
                                               float* __restrict__ partials,
                                               int* __restrict__ edges,
                                               int* __restrict__ rootCnt,
                                               int* __restrict__ rootList,
                                               unsigned int* __restrict__ counter) {
    __shared__ int lab[TILE * TILE];   // 16 KB
    __shared__ float swf[8];
    __shared__ int rootc;
    int tile = blockIdx.x;
    int img = tile >> 6;
    int t = tile & (TPI - 1);
    int ty = t >> 3, tx = t & 7;
    int baseLocal = (ty * TILE) * IMG_W + tx * TILE;  // image-local origin
    const float* pi = pred + ((size_t)img << LOGHW);
    int* Li = L + ((size_t)img << LOGHW);
    int tid = threadIdx.x;
    int lane = tid & 63, wave = tid >> 6;             // wave 0..7
    if (tid == 0) rootc = 0;

    float acc = 0.0f;
    // ---- pass 1: row-run labels via ballot (wave w handles rows r%8==w) ----
#pragma unroll
    for (int j = 0; j < 8; j++) {
        int row = wave + j * 8;
        float p = pi[baseLocal + row * IMG_W + lane];
        acc += fmaxf(__logf(1.0f - p), -100.0f);   // 1-p exact for p>=0.5
        bool fg = (p >= 0.5f);
        unsigned long long bal = __ballot(fg);
        unsigned long long starts = bal & ~(bal << 1);
        unsigned long long maskle =
            (lane == 63) ? ~0ULL : ((1ULL << (lane + 1)) - 1ULL);
        int lb = -1;
        if (fg) {
            unsigned long long pre = starts & maskle;   // nonzero when fg
            lb = row * TILE + (63 - __builtin_clzll(pre));
        }
        lab[row * TILE + lane] = lb;
    }
    __syncthreads();
    // ---- pass 2: vertical unites, one per contact-run ----------------------
#pragma unroll
    for (int j = 0; j < 8; j++) {
        int row = wave + j * 8;
        if (row == 0) continue;                   // wave-uniform
        int i = row * TILE + lane;
        bool c = (lab[i] >= 0) && (lab[i - TILE] >= 0);
        unsigned long long cb = __ballot(c);
        unsigned long long cs = cb & ~(cb << 1);  // first lane of each contact
        if ((cs >> lane) & 1ULL) uf_unite(lab, i, i - TILE);
    }
    __syncthreads();
    // ---- pass 3a: run-starts chase to root + sparse root export ------------
    int* rl = rootList + (size_t)tile * RTSTRIDE;
#pragma unroll
    for (int j = 0; j < 8; j++) {
        int row = wave + j * 8;
        int i = row * TILE + lane;
        bool fg = (lab[i] >= 0);
        unsigned long long bal = __ballot(fg);
        unsigned long long st = bal & ~(bal << 1);
        if ((st >> lane) & 1ULL) {
            int x = i, p = lab[x];
            while (p != x) {
                int g = lab[p];
                lab[x] = g;          // halving: benign race, ancestors only
                x = g;
                p = lab[x];
            }
            lab[i] = x;              // full compress for the start entry
            if (x == i) {            // i is a LOCAL ROOT (~270/tile)
                int b = atomicAdd(&rootc, 1);   // LDS atomic (per-block, safe)
                rl[b] = baseLocal + (i >> 6) * IMG_W + (i & 63);
            }
        }
    }
    __syncthreads();
    // ---- pass 3b: b128 gather + global write (int4) ------------------------
#pragma unroll
    for (int j = 0; j < 2; j++) {
        int i4 = (tid + j * 512) * 4;
        int4 s4 = *(const int4*)&lab[i4];        // one ds_read_b128
        const int* sp = (const int*)&s4;
        int4 o;
        int* op = (int*)&o;
#pragma unroll
        for (int k = 0; k < 4; k++) {
            int s = sp[k];
            if (s < 0) op[k] = -1;
            else {
                int r = lab[s];                  // root (starts compressed)
                op[k] = baseLocal + (r >> 6) * IMG_W + (r & 63);
            }
        }
        *(int4*)(Li + baseLocal + (i4 >> 6) * IMG_W + (i4 & 63)) = o;
    }
    // ---- edge export: 4 x 64 labels, coalesced -----------------------------
    if (tid < 256) {
        int e = tid >> 6;                        // 0=T,1=B,2=L,3=R
        int q = tid & 63;
        int px = (e == 0) ? q
               : (e == 1) ? (63 * TILE + q)
               : (e == 2) ? (q * TILE)
               :            (q * TILE + 63);
        int s = lab[px];
        int val = -1;
        if (s >= 0) {
            int r = lab[s];
            val = baseLocal + (r >> 6) * IMG_W + (r & 63);
        }
        edges[e * EDGE_N + tile * 64 + q] = val;
    }
    // ---- base BCE: wave shuffle reduce (1 barrier) -------------------------
#pragma unroll
    for (int o = 32; o > 0; o >>= 1) acc += __shfl_down(acc, o);
    if (lane == 0) swf[wave] = acc;
    __syncthreads();                             // also orders rootc/rl
    if (tid == 0) {
        float s = 0.0f;
#pragma unroll
        for (int w = 0; w < 8; w++) s += swf[w];
        partials[blockIdx.x] = s;
        rootCnt[tile] = rootc;
        if (blockIdx.x == 0) *counter = 0u;      // ws is 0xAA-poisoned
    }
}

// ---------------- K2: cross-tile border unites from compact edges -----------
// One wave per tile-pair (3584 waves, full TLP). Plain unites, no exports.
__global__ __launch_bounds__(256) void k_border(const int* __restrict__ edges,
                                                int* __restrict__ L) {
    int gid = blockIdx.x * blockDim.x + threadIdx.x;
    int pair = gid >> 6;                 // wave-uniform
    int lane = gid & 63;
    int a, b, img;
    if (pair < NIMG * 56) {              // vertical: (ty,tx)-(ty,tx+1)
        img = pair / 56;
        int w = pair - img * 56;
        int ty = w / 7, tx = w - ty * 7;
        int tl = img * TPI + ty * 8 + tx;
        a = edges[3 * EDGE_N + tl * 64 + lane];        // right edge of left
        b = edges[2 * EDGE_N + (tl + 1) * 64 + lane];  // left edge of right
    } else {                             // horizontal: (ty,tx)-(ty+1,tx)
        int p2 = pair - NIMG * 56;
        img = p2 / 56;
        int w = p2 - img * 56;
        int ty = w >> 3, tx = w & 7;
        int tu = img * TPI + ty * 8 + tx;
        a = edges[1 * EDGE_N + tu * 64 + lane];        // bottom edge of upper
        b = edges[0 * EDGE_N + (tu + 8) * 64 + lane];  // top edge of lower
    }
    bool c = (a >= 0) && (b >= 0);
    unsigned long long cb = __ballot(c);
    unsigned long long cs = cb & ~(cb << 1);           // contact-run starts
    if ((cs >> lane) & 1ULL)
        uf_unite(L + ((size_t)img << LOGHW), a, b);
}

// ---------------- K2b: per-tile survivor probe (2048 blocks, 1 wave each) ---
// Root flags (L[r]==r) are invariant under path compression. Global roots
// are exactly the surviving local roots. ~270 probes/tile over 64 lanes =
// ~5 rounds; scattered loads are L2/L3-resident (L just written). Wave
// shuffle reduce, no barriers, no atomics. All 2048 outputs written
// unconditionally (ws is poisoned).
__global__ __launch_bounds__(64) void k_probe(const int* __restrict__ rootCnt,
                                              const int* __restrict__ rootList,
                                              const int* __restrict__ L,
                                              int* __restrict__ cntT,
                                              int* __restrict__ maxT) {
    int tile = blockIdx.x;
    int img = tile >> 6;
    const int* Li = L + ((size_t)img << LOGHW);
    const int* rl = rootList + (size_t)tile * RTSTRIDE;
    int rc = rootCnt[tile];
    int lane = threadIdx.x;
    int cnt = 0, mx = -1;
    for (int k = lane; k < rc; k += 64) {
        int r = rl[k];
        if (Li[r] == r) { cnt++; mx = max(mx, r); }
    }
#pragma unroll
    for (int o = 32; o > 0; o >>= 1) {
        cnt += __shfl_down(cnt, o);
        mx = max(mx, __shfl_down(mx, o));
    }
    if (lane == 0) { cntT[tile] = cnt; maxT[tile] = mx; }
}

// ---------------- K3: tiny stats reduce + rv + final reduce -----------------
// One block (512 thr) per image. ONLY O(64) reads in the common path (R19
// lesson: 32-block grids may not run memory loops). num = sum cntT;
// last_root = max maxT. v = last_root if >=1; else lazy minFg scan / 1.
// rv >= 0 (v<=num, never on this input) falls back to in-block full-L
// selection + correction scan. Last of the 32 blocks (32-way counter — the
// only safe handshake) reduces k_local's 2048 base partials + 32 corrections.
__global__ __launch_bounds__(512) void k_tail(const int* __restrict__ cntT,
                                              const int* __restrict__ maxT,
                                              const int* __restrict__ L,
                                              const float* __restrict__ pred,
                                              const float* __restrict__ partials,
                                              float* __restrict__ corr,
                                              unsigned int* __restrict__ counter,
                                              float* __restrict__ out) {
    __shared__ int sc[512], sm[512];
    __shared__ int result;
    __shared__ float sf[512];
    __shared__ double sd[512];
    __shared__ unsigned int oldc;
    int img = blockIdx.x, t = threadIdx.x;
    const int* Li = L + ((size_t)img << LOGHW);

    sc[t] = (t < TPI) ? cntT[img * TPI + t] : 0;
    sm[t] = (t < TPI) ? maxT[img * TPI + t] : -1;
    if (t == 0) result = -2;
    __syncthreads();
    for (int s = 256; s > 0; s >>= 1) {
        if (t < s) { sc[t] += sc[t + s]; sm[t] = max(sm[t], sm[t + s]); }
        __syncthreads();
    }
    int num = sc[0], last_root = sm[0];
    int v;
    if (last_root >= 1) {                // block-uniform (common case)
        v = last_root;
    } else {
        // rare: lazy minFg = first fg index >= 1 (coalesced Li scan)
        __syncthreads();                 // sc reuse
        int mn = HW;
        for (int i0 = t * 4; i0 < HW; i0 += 2048) {
            int4 l4 = *(const int4*)(Li + i0);
            if (l4.x >= 0 && i0 >= 1) mn = min(mn, i0);
            if (l4.y >= 0) mn = min(mn, i0 + 1);
            if (l4.z >= 0) mn = min(mn, i0 + 2);
            if (l4.w >= 0) mn = min(mn, i0 + 3);
        }
        sc[t] = mn;
        __syncthreads();
        for (int s = 256; s > 0; s >>= 1) {
            if (t < s) sc[t] = min(sc[t], sc[t + s]);
            __syncthreads();
        }
        mn = sc[0];
        v = (last_root == 0) ? ((mn < HW) ? mn : 1) : 1;
        __syncthreads();
    }

    // ---- rare path: select v-th surviving root in raster order -------------
    if (v >= 1 && v <= num) {            // block-uniform branch
        __syncthreads();                 // sc reuse
        int base = t * (HW / 512);       // contiguous 512-px raster range
        int c = 0;
        for (int j = 0; j < 128; j++) {
            int off = base + j * 4;
            int4 l4 = *(const int4*)(Li + off);
            c += (l4.x == off) + (l4.y == off + 1)
               + (l4.z == off + 2) + (l4.w == off + 3);
        }
        sc[t] = c;
        __syncthreads();
        for (int off = 1; off < 512; off <<= 1) {
            int v2 = (t >= off) ? sc[t - off] : 0;
            __syncthreads();
            sc[t] += v2;
            __syncthreads();
        }
        int inc = sc[t], exc = inc - c;
        if (exc < v && v <= inc) {       // my range holds the v-th root
            int need = v - exc, run = 0;
            for (int j = 0; j < 128; j++) {
                int off = base + j * 4;
                int4 l4 = *(const int4*)(Li + off);
                if (l4.x == off)     { run++; if (run == need) result = off; }
                if (l4.y == off + 1) { run++; if (run == need) result = off + 1; }
                if (l4.z == off + 2) { run++; if (run == need) result = off + 2; }
                if (l4.w == off + 3) { run++; if (run == need) result = off + 3; }
                if (run >= need) break;
            }
        }
        __syncthreads();
    }
    int rvv = result;
    float blocksum = 0.0f;
    if (rvv >= 0) {                      // rare path: scan whole image
        const float* pi = pred + ((size_t)img << LOGHW);
        float acc = 0.0f;
        for (int it = 0; it < HW / 2048; it++) {
            int off = it * 2048 + t * 4;
            float4 p4 = *(const float4*)(pi + off);
            int4 l4 = *(const int4*)(Li + off);
            const float* pp = (const float*)&p4;
            const int* lp = (const int*)&l4;
#pragma unroll
            for (int k = 0; k < 4; k++) {
                int p = lp[k];
                if (p < 0) continue;
                int x = p, q = Li[x];
                while (q != x) { x = q; q = Li[x]; }
                if (x == rvv) {
                    float pr = pp[k];
                    acc += fmaxf(__logf(pr), -100.0f)
                         - fmaxf(__logf(1.0f - pr), -100.0f);
                }
            }
        }
        sf[t] = acc;
        __syncthreads();
        for (int s = 256; s > 0; s >>= 1) {
            if (t < s) sf[t] += sf[t + s];
            __syncthreads();
        }
        blocksum = sf[0];
    }
    if (t == 0) {
        __hip_atomic_store(&corr[img], blocksum, __ATOMIC_RELAXED,
                           __HIP_MEMORY_SCOPE_AGENT);
        oldc = __hip_atomic_fetch_add(counter, 1u, __ATOMIC_ACQ_REL,
                                      __HIP_MEMORY_SCOPE_AGENT);
    }
    __syncthreads();
    if (oldc != NIMG - 1) return;
    // ---- last of 32 blocks: final reduce -----------------------------------
    double acc = 0.0;
#pragma unroll
    for (int j = 0; j < 4; j++) acc += (double)partials[t + j * 512];
    if (t < NIMG)
        acc += (double)__hip_atomic_load(&corr[t], __ATOMIC_ACQUIRE,
                                         __HIP_MEMORY_SCOPE_AGENT);
    sd[t] = acc;
    __syncthreads();
    for (int s = 256; s > 0; s >>= 1) {
        if (t < s) sd[t] += sd[t + s];
        __syncthreads();
    }
    if (t == 0) out[0] = (float)(-sd[0] / (double)NTOT);
}

extern "C" void kernel_launch(void* const* d_in, const int* in_sizes, int n_in,
                              void* d_out, int out_size, void* d_ws, size_t ws_size,
                              hipStream_t stream) {
    const float* pred = (const float*)d_in[0];
    float* out = (float*)d_out;

    char* ws = (char*)d_ws;
    int* L = (int*)ws;                                        // 33.5 MB
    int* edges = (int*)(ws + (size_t)NTOT * 4);               // 2 MB (4 dirs)
    int* rootList = edges + 4 * EDGE_N;                       // 16.8 MB
    int* rootCnt = rootList + (size_t)NTILE * RTSTRIDE;       // 8 KB
    int* cntT = rootCnt + NTILE;                              // 8 KB
    int* maxT = cntT + NTILE;                                 // 8 KB
    float* partials = (float*)(maxT + NTILE);                 // 8 KB
    float* corr = partials + NTILE;                           // 128 B
    unsigned int* counter = (unsigned int*)(corr + NIMG);     // 4 B

    k_local<<<dim3(NTILE), dim3(512), 0, stream>>>(pred, L, partials, edges,
                                                   rootCnt, rootList, counter);
    k_border<<<dim3(NPAIR * 64 / 256), dim3(256), 0, stream>>>(edges, L);
    k_probe<<<dim3(NTILE), dim3(64), 0, stream>>>(rootCnt, rootList, L,
                                                  cntT, maxT);
    k_tail<<<dim3(NIMG), dim3(512), 0, stream>>>(cntT, maxT, L, pred,
                                                 partials, corr, counter, out);
}